// Round 7
// baseline (355.333 us; speedup 1.0000x reference)
//
#include <hip/hip_runtime.h>
#include <math.h>

#define IMG_H 1024
#define IMG_W 1024
#define OUT_H 1025
#define OUT_W 1025
#define NIMG  16
#define TOTAL ((size_t)NIMG * OUT_H * OUT_W)

#define SW      60                       // output cols per wave strip
#define NSTRIP  18                       // ceil(1025/60)
#define CHUNK   41                       // rows per wave chunk (25*41 = 1025 exactly)
#define NCHUNK  25
#define WAVES_PER_IMG (NSTRIP * NCHUNK)  // 450
#define TOTAL_WAVES   (NIMG * WAVES_PER_IMG)  // 7200
#define NTHREADS 128                     // 2 waves/block -> 3600 blocks

// Map bp (double-reflect-padded) row/col index k in [0,1026] to source image index.
__device__ __forceinline__ int refl(int k) {
    if (k >= 2) return (k <= 1025) ? (k - 2) : 1022;
    return k;
}

// Generic sobel at output (i,j) — exact f32 op order (bit-matched np in r1-r6).
__device__ __forceinline__ void sobel_generic(const float* __restrict__ img, int i, int j,
                                              float& gx, float& gy) {
    int r0 = refl(i), r1 = refl(i + 1), r2 = refl(i + 2);
    int c0 = refl(j), c1 = refl(j + 1), c2 = refl(j + 2);
    const float* p0 = img + r0 * IMG_W;
    const float* p1 = img + r1 * IMG_W;
    const float* p2 = img + r2 * IMG_W;
    float v00 = p0[c0], v01 = p0[c1], v02 = p0[c2];
    float v10 = p1[c0],               v12 = p1[c2];
    float v20 = p2[c0], v21 = p2[c1], v22 = p2[c2];

    float t = -v00;
    t = __fadd_rn(t, v02);
    t = __fadd_rn(t, -2.0f * v10);
    t = __fadd_rn(t, 2.0f * v12);
    t = __fadd_rn(t, -v20);
    gx = __fadd_rn(t, v22);

    t = -v00;
    t = __fadd_rn(t, -2.0f * v01);
    t = __fadd_rn(t, -v02);
    t = __fadd_rn(t, v20);
    t = __fadd_rn(t, 2.0f * v21);
    gy = __fadd_rn(t, v22);
}

// Sobel from 9 register values (identical op order).
__device__ __forceinline__ void sobel9(float v00, float v01, float v02,
                                       float v10, float v12,
                                       float v20, float v21, float v22,
                                       float& gx, float& gy) {
    float s = -v00;
    s = __fadd_rn(s, v02);
    s = __fadd_rn(s, -2.0f * v10);
    s = __fadd_rn(s, 2.0f * v12);
    s = __fadd_rn(s, -v20);
    gx = __fadd_rn(s, v22);

    s = -v00;
    s = __fadd_rn(s, -2.0f * v01);
    s = __fadd_rn(s, -v02);
    s = __fadd_rn(s, v20);
    s = __fadd_rn(s, 2.0f * v21);
    gy = __fadd_rn(s, v22);
}

// Exact reference binning (double atan2 -> f32 chain). Bit-matched np in r1.
__device__ int classify_slow(float gx, float gy) {
    float t = (float)atan2((double)gx, (double)gy);
    float deg = __fmul_rn(t, (float)(180.0 / M_PI));
    float th = __fadd_rn(deg, 90.0f);
    th = fmodf(th, 180.0f);
    if (th < 0.0f) th += 180.0f;
    if (th < 22.5f || th >= 157.5f) return 0;
    if (th < 67.5f) return 1;
    if (th < 112.5f) return 2;
    return 3;
}

// Branchless fast binning with guard band; rare lanes defer to the exact chain.
__device__ __forceinline__ int classify(float gx, float gy) {
    float ax = fabsf(gx), ay = fabsf(gy);
    const float T22_LO = 0.414172141e0f;
    const float T22_HI = 0.414254984e0f;
    const float T67_LO = 2.413972141e0f;
    const float T67_HI = 2.414454984e0f;

    bool in22 = (ax > ay * T22_LO) && (ax < ay * T22_HI);
    bool in67 = (ax > ay * T67_LO) && (ax < ay * T67_HI);
    if (__builtin_expect(in22 || in67, 0))
        return classify_slow(gx, gy);

    unsigned s = (__float_as_uint(gx) ^ __float_as_uint(gy)) >> 31;
    int diag = s ? 1 : 3;
    return (ax <= ay * T22_LO) ? 2 : ((ax >= ay * T67_HI) ? 0 : diag);
}

__device__ __forceinline__ float mag(float gx, float gy) {
    return __fsqrt_rn(__fadd_rn(__fmul_rn(gx, gx), __fmul_rn(gy, gy)));
}

__global__ __launch_bounds__(NTHREADS, 8) void canny_kernel(const float* __restrict__ images,
                                                            float* __restrict__ out) {
    const int wid  = blockIdx.x * (NTHREADS / 64) + (threadIdx.x >> 6);
    const int lane = threadIdx.x & 63;
    const int n    = wid / WAVES_PER_IMG;
    const int rem  = wid - n * WAVES_PER_IMG;
    const int s    = rem / NCHUNK;
    const int k    = rem - s * NCHUNK;

    const float* img = images + (size_t)n * (IMG_H * IMG_W);
    const int gc0  = s * SW - 1;             // g-column of lane 0
    const int gcol = gc0 + lane;             // this lane's g column (== output col)
    const int Y0   = k * CHUNK;              // first output row of this chunk

    int lc = gcol - 2;                       // image column this lane loads
    lc = lc < 0 ? 0 : (lc > 1023 ? 1023 : lc);

    const bool gv      = (lane <= 61) && (gcol >= 0) && (gcol <= 1024);
    const bool needfix = gv && (gcol <= 1 || gcol == 1024);  // reflection cols
    const bool ov      = (lane >= 1) && (lane <= 60) && (gcol <= 1024);

    // rolling image-row registers: A/B/C = img rows refl(r), refl(r+1), refl(r+2)
    // for the g-row r being computed; L = own col (gcol-2), C = +1, R = +2.
    float AL, AC, AR, BL, BC, BR, CL, CC, CR, pend;

    #define LDROW(mr) (img[(mr) * IMG_W + lc])
    #define SHUF(L, C, R) do { C = __shfl_down(L, 1); R = __shfl_down(L, 2); } while (0)

    // g + bin at g-row rg from current A/B/C registers (+ masked edge fixup).
    #define COMPUTE_G(rg, gdst, bdst) do {                                   \
        float _gx, _gy;                                                      \
        sobel9(AL, AC, AR, BL, BR, CL, CC, CR, _gx, _gy);                    \
        if (needfix) sobel_generic(img, (rg), gcol, _gx, _gy);               \
        gdst = mag(_gx, _gy);                                                \
        bdst = (unsigned)classify(_gx, _gy);                                 \
        if (!gv) { gdst = 0.0f; bdst = 255u; }                               \
    } while (0)

    float gm1v, g0v, gp1v;
    unsigned bm1, b0, bp1;

    // ---- warm-up: gm1 = g(Y0-1), g0 = g(Y0) ----
    if (k == 0) {
        AL = LDROW(0); SHUF(AL, AC, AR);     // refl(0)=0
        BL = LDROW(1); SHUF(BL, BC, BR);     // refl(1)=1
        CL = AL; CC = AC; CR = AR;           // refl(2)=0
        COMPUTE_G(0, g0v, b0);
        gm1v = 0.0f; bm1 = 255u;             // row -1: out of bounds, never matches
    } else {
        int r0 = Y0 - 1;                     // >= 40, interior
        AL = LDROW(r0 - 2); SHUF(AL, AC, AR);
        BL = LDROW(r0 - 1); SHUF(BL, BC, BR);
        CL = LDROW(r0);     SHUF(CL, CC, CR);
        COMPUTE_G(r0, gm1v, bm1);
        AL = BL; AC = BC; AR = BR;  BL = CL; BC = CC; BR = CR;
        CL = LDROW(refl(r0 + 3)); SHUF(CL, CC, CR);
        COMPUTE_G(Y0, g0v, b0);
    }
    {
        int pr = Y0 + 3; pr = pr > 1026 ? 1026 : pr;
        pend = LDROW(refl(pr));              // row needed by first loop iteration
    }

    float* const out_i = out;
    float* const out_w = out + TOTAL;
    float* const out_s = out + 2 * TOTAL;
    int o = (n * OUT_H + Y0) * OUT_W + gcol;

    for (int y = Y0; y < Y0 + CHUNK; ++y) {
        int yn = y + 1;
        if (yn <= 1024) {
            AL = BL; AC = BC; AR = BR;  BL = CL; BC = CC; BR = CR;
            CL = pend; SHUF(CL, CC, CR);
            int pr = y + 4; pr = pr > 1026 ? 1026 : pr;   // prefetch next row
            pend = LDROW(refl(pr));
            COMPUTE_G(yn, gp1v, bp1);
        } else {
            gp1v = 0.0f; bp1 = 255u;         // row 1025: out of bounds
        }

        // ---- NMS at output row y (register/shuffle only) ----
        unsigned pk  = bm1 | (b0 << 8) | (bp1 << 16);
        float g0E = __shfl_down(g0v, 1),  g0W = __shfl_up(g0v, 1);
        float gmE = __shfl_down(gm1v, 1), gmW = __shfl_up(gm1v, 1);
        float gpE = __shfl_down(gp1v, 1), gpW = __shfl_up(gp1v, 1);
        unsigned pkE = (unsigned)__shfl_down((int)pk, 1);
        unsigned pkW = (unsigned)__shfl_up((int)pk, 1);

        unsigned bc = b0;
        // +dir: bin0 E(row), bin1 SW, bin2 S, bin3 SE
        float    n1 = bc == 0 ? g0E : (bc == 1 ? gpW : (bc == 2 ? gp1v : gpE));
        unsigned q1 = bc == 0 ? pkE : (bc == 1 ? pkW : (bc == 2 ? pk  : pkE));
        unsigned s1 = bc == 0 ? ((q1 >> 8) & 255u) : ((q1 >> 16) & 255u);
        // -dir: bin0 W(row), bin1 NE, bin2 N, bin3 NW
        float    n2 = bc == 0 ? g0W : (bc == 1 ? gmE : (bc == 2 ? gm1v : gmW));
        unsigned q2 = bc == 0 ? pkW : (bc == 1 ? pkE : (bc == 2 ? pk  : pkW));
        unsigned s2 = bc == 0 ? ((q2 >> 8) & 255u) : (q2 & 255u);

        float m1 = (s1 == bc) ? n1 : 0.0f;
        float m2 = (s2 == bc) ? n2 : 0.0f;
        float mx = fmaxf(m1, m2);
        float e  = (g0v >= mx) ? g0v : 0.0f;

        if (ov) {
            out_i[o] = (e >= 50.0f) ? 255.5f : 0.0f;
            out_w[o] = (e >= 50.0f && e < 100.0f) ? 255.0f : 0.0f;
            out_s[o] = (e >= 100.0f) ? 255.0f : 0.0f;
        }
        o += OUT_W;
        gm1v = g0v; bm1 = b0;  g0v = gp1v; b0 = bp1;
    }
    #undef LDROW
    #undef SHUF
    #undef COMPUTE_G
}

extern "C" void kernel_launch(void* const* d_in, const int* in_sizes, int n_in,
                              void* d_out, int out_size, void* d_ws, size_t ws_size,
                              hipStream_t stream) {
    const float* images = (const float*)d_in[0];
    float* out = (float*)d_out;
    int blocks = TOTAL_WAVES / (NTHREADS / 64);   // 3600
    canny_kernel<<<blocks, NTHREADS, 0, stream>>>(images, out);
}